// Round 1
// baseline (9000.052 us; speedup 1.0000x reference)
//
#include <hip/hip_runtime.h>
#include <math.h>

#define NPTS_MAX 16384
#define PPB 2048
#define NBATCH 8
#define KNN 20

// ---------------------------------------------------------------------------
// Generic GEMM: Y[i][m] = sum_k X[i*ldx+k] * W[m*ldw+k] + bias[m]
// block (16,16), tiles of K=32 staged in LDS.
// ---------------------------------------------------------------------------
__global__ __launch_bounds__(256) void gemm_kernel(
    const float* __restrict__ X, int ldx,
    const float* __restrict__ W, int ldw,
    const float* __restrict__ bias,
    float* __restrict__ Y, int ldy,
    int N, int D, int M) {
  __shared__ float Xs[16][33];
  __shared__ float Ws[16][33];
  int tx = threadIdx.x;   // m
  int ty = threadIdx.y;   // i
  int i0 = blockIdx.y * 16;
  int m0 = blockIdx.x * 16;
  int t = ty * 16 + tx;
  float acc = 0.f;
  for (int k0 = 0; k0 < D; k0 += 32) {
    for (int e = t; e < 512; e += 256) {
      int r = e >> 5, c = e & 31;
      int k = k0 + c;
      int i = i0 + r;
      int m = m0 + r;
      Xs[r][c] = (i < N && k < D) ? X[(size_t)i * ldx + k] : 0.f;
      Ws[r][c] = (m < M && k < D) ? W[(size_t)m * ldw + k] : 0.f;
    }
    __syncthreads();
#pragma unroll
    for (int kk = 0; kk < 32; ++kk) acc += Xs[ty][kk] * Ws[tx][kk];
    __syncthreads();
  }
  int i = i0 + ty, m = m0 + tx;
  if (i < N && m < M)
    Y[(size_t)i * ldy + m] = acc + (bias ? bias[m] : 0.f);
}

// ---------------------------------------------------------------------------
// h0 = [pos | x | feats]  (134 dims), feats lives in catbuf col 448, ld 576
// ---------------------------------------------------------------------------
__global__ __launch_bounds__(192) void h0_kernel(
    const float* __restrict__ pos, const float* __restrict__ xin,
    const float* __restrict__ catbuf, float* __restrict__ h0) {
  int i = blockIdx.x;
  int d = threadIdx.x;
  if (d < 3)        h0[(size_t)i * 134 + d] = pos[i * 3 + d];
  else if (d < 6)   h0[(size_t)i * 134 + d] = xin[i * 3 + d - 3];
  else if (d < 134) h0[(size_t)i * 134 + d] = catbuf[(size_t)i * 576 + 448 + (d - 6)];
}

// ---------------------------------------------------------------------------
// sq[i] = sum_k X[i][k]^2   (one 64-lane wave per point)
// ---------------------------------------------------------------------------
__global__ __launch_bounds__(64) void sq_kernel(
    const float* __restrict__ X, int ldx, int D, float* __restrict__ sq) {
  int i = blockIdx.x;
  int t = threadIdx.x;
  float s = 0.f;
  for (int k = t; k < D; k += 64) {
    float v = X[(size_t)i * ldx + k];
    s += v * v;
  }
  for (int off = 32; off > 0; off >>= 1) s += __shfl_down(s, off);
  if (t == 0) sq[i] = s;
}

// ---------------------------------------------------------------------------
// KNN: per point i, top-KNN smallest dist(i,j) within its batch of PPB points.
// dist = sq[i] + sq[j] - 2*dot(x_i, x_j).  Stable tie-break: lowest j wins.
// ---------------------------------------------------------------------------
__global__ __launch_bounds__(256) void knn_kernel(
    const float* __restrict__ X, int ldx, int D,
    const float* __restrict__ sq, int* __restrict__ idx) {
  int i = blockIdx.x;
  int b = i / PPB;
  int base = b * PPB;
  __shared__ float xs[160];
  __shared__ float dist[PPB];
  __shared__ float rv[256];
  __shared__ int ri[256];
  int t = threadIdx.x;
  for (int k = t; k < D; k += 256) xs[k] = X[(size_t)i * ldx + k];
  __syncthreads();
  float sqi = sq[i];
  for (int j = t; j < PPB; j += 256) {
    const float* xj = X + (size_t)(base + j) * ldx;
    float dot = 0.f;
    for (int k = 0; k < D; ++k) dot += xs[k] * xj[k];
    dist[j] = sqi + sq[base + j] - 2.f * dot;
  }
  __syncthreads();
  for (int s = 0; s < KNN; ++s) {
    float bv = INFINITY;
    int bi = 0x7fffffff;
    for (int j = t; j < PPB; j += 256) {
      float v = dist[j];
      if (v < bv || (v == bv && j < bi)) { bv = v; bi = j; }
    }
    rv[t] = bv; ri[t] = bi;
    __syncthreads();
    for (int off = 128; off > 0; off >>= 1) {
      if (t < off) {
        float v2 = rv[t + off]; int i2 = ri[t + off];
        if (v2 < rv[t] || (v2 == rv[t] && i2 < ri[t])) { rv[t] = v2; ri[t] = i2; }
      }
      __syncthreads();
    }
    if (t == 0) {
      idx[(size_t)i * KNN + s] = base + ri[0];
      dist[ri[0]] = INFINITY;
    }
    __syncthreads();
  }
}

// ---------------------------------------------------------------------------
// EdgeConv epilogue: Y[i][m] = A[i][m] + b[m] - Pb[i][m] + max_kk Pb[nb][m]
// ---------------------------------------------------------------------------
__global__ __launch_bounds__(256) void edge_out_kernel(
    const float* __restrict__ A, const float* __restrict__ Pb, int M,
    const float* __restrict__ bias, const int* __restrict__ idx,
    float* __restrict__ Y, int ldy) {
  int i = blockIdx.x;
  int t = threadIdx.x;
  __shared__ int nbs[KNN];
  if (t < KNN) nbs[t] = idx[(size_t)i * KNN + t];
  __syncthreads();
  for (int m = t; m < M; m += 256) {
    float mx = -INFINITY;
#pragma unroll
    for (int kk = 0; kk < KNN; ++kk)
      mx = fmaxf(mx, Pb[(size_t)nbs[kk] * M + m]);
    Y[(size_t)i * ldy + m] = A[(size_t)i * M + m] + bias[m] - Pb[(size_t)i * M + m] + mx;
  }
}

// ---------------------------------------------------------------------------
// fc1 GEMM (576 -> 1024) with per-16-point-tile max epilogue.
// grid: (M/16, PPB/16, NBATCH)
// ---------------------------------------------------------------------------
__global__ __launch_bounds__(256) void fc1max_kernel(
    const float* __restrict__ X, int ldx,
    const float* __restrict__ W, int ldw,
    const float* __restrict__ bias,
    float* __restrict__ partial, int D, int M) {
  __shared__ float Xs[16][33];
  __shared__ float Ws[16][33];
  __shared__ float red[16][17];
  int tx = threadIdx.x, ty = threadIdx.y;
  int b = blockIdx.z;
  int pt = blockIdx.y;
  int i0 = b * PPB + pt * 16;
  int m0 = blockIdx.x * 16;
  int t = ty * 16 + tx;
  float acc = 0.f;
  for (int k0 = 0; k0 < D; k0 += 32) {
    for (int e = t; e < 512; e += 256) {
      int r = e >> 5, c = e & 31;
      int k = k0 + c;
      Xs[r][c] = (k < D) ? X[(size_t)(i0 + r) * ldx + k] : 0.f;
      Ws[r][c] = (k < D) ? W[(size_t)(m0 + r) * ldw + k] : 0.f;
    }
    __syncthreads();
#pragma unroll
    for (int kk = 0; kk < 32; ++kk) acc += Xs[ty][kk] * Ws[tx][kk];
    __syncthreads();
  }
  acc += bias[m0 + tx];
  red[ty][tx] = acc;
  __syncthreads();
  for (int off = 8; off > 0; off >>= 1) {
    if (ty < off) red[ty][tx] = fmaxf(red[ty][tx], red[ty + off][tx]);
    __syncthreads();
  }
  if (ty == 0)
    partial[((size_t)b * (PPB / 16) + pt) * 1024 + m0 + tx] = red[0][tx];
}

__global__ __launch_bounds__(256) void gmax_kernel(
    const float* __restrict__ partial, float* __restrict__ g) {
  int b = blockIdx.y;
  int m = blockIdx.x * 256 + threadIdx.x;
  float mx = -INFINITY;
  for (int pt = 0; pt < PPB / 16; ++pt)
    mx = fmaxf(mx, partial[((size_t)b * (PPB / 16) + pt) * 1024 + m]);
  g[b * 1024 + m] = mx;
}

// ---------------------------------------------------------------------------
// Tiny per-batch MLP layer: Y[b][m] = (relu?) dot(X[b], W[m]) + bias[m]
// ---------------------------------------------------------------------------
__global__ __launch_bounds__(256) void mlp_kernel(
    const float* __restrict__ X, const float* __restrict__ W,
    const float* __restrict__ bias, float* __restrict__ Y,
    int D, int M, int do_relu) {
  int b = blockIdx.y;
  int m = blockIdx.x * 256 + threadIdx.x;
  if (m >= M) return;
  const float* xr = X + (size_t)b * D;
  const float* wr = W + (size_t)m * D;
  float acc = 0.f;
  for (int k = 0; k < D; ++k) acc += xr[k] * wr[k];
  acc += bias[m];
  if (do_relu) acc = fmaxf(acc, 0.f);
  Y[(size_t)b * M + m] = acc;
}

// ---------------------------------------------------------------------------
// Final 256->23 + log_softmax.  One block per batch.
// ---------------------------------------------------------------------------
__global__ __launch_bounds__(64) void final_kernel(
    const float* __restrict__ X, const float* __restrict__ W,
    const float* __restrict__ bias, float* __restrict__ out) {
  int b = blockIdx.x;
  int t = threadIdx.x;
  __shared__ float lg[23];
  if (t < 23) {
    const float* xr = X + (size_t)b * 256;
    const float* wr = W + (size_t)t * 256;
    float acc = bias[t];
    for (int k = 0; k < 256; ++k) acc += xr[k] * wr[k];
    lg[t] = acc;
  }
  __syncthreads();
  if (t == 0) {
    float mx = lg[0];
    for (int c = 1; c < 23; ++c) mx = fmaxf(mx, lg[c]);
    float s = 0.f;
    for (int c = 0; c < 23; ++c) s += expf(lg[c] - mx);
    float lse = mx + logf(s);
    for (int c = 0; c < 23; ++c) out[b * 23 + c] = lg[c] - lse;
  }
}

// ---------------------------------------------------------------------------

extern "C" void kernel_launch(void* const* d_in, const int* in_sizes, int n_in,
                              void* d_out, int out_size, void* d_ws, size_t ws_size,
                              hipStream_t stream) {
  const float* pos      = (const float*)d_in[0];
  const float* xin      = (const float*)d_in[1];
  const float* features = (const float*)d_in[2];
  // d_in[3] = batch (unused; shapes are static)
  const float* Wf   = (const float*)d_in[4];
  const float* bf   = (const float*)d_in[5];
  const float* W1   = (const float*)d_in[6];
  const float* b1   = (const float*)d_in[7];
  const float* W2   = (const float*)d_in[8];
  const float* b2   = (const float*)d_in[9];
  const float* W3   = (const float*)d_in[10];
  const float* b3   = (const float*)d_in[11];
  const float* Wfc1 = (const float*)d_in[12];
  const float* bfc1 = (const float*)d_in[13];
  const float* Wfa  = (const float*)d_in[14];
  const float* bfa  = (const float*)d_in[15];
  const float* Wfb  = (const float*)d_in[16];
  const float* bfb  = (const float*)d_in[17];
  const float* Wfc  = (const float*)d_in[18];
  const float* bfc  = (const float*)d_in[19];
  float* out = (float*)d_out;

  const int N = in_sizes[0] / 3;   // 16384

  // workspace layout (bytes)
  char* base = (char*)d_ws;
  size_t off = 0;
  auto alloc = [&](size_t bytes) {
    void* p = base + off;
    off += (bytes + 255) & ~(size_t)255;
    return p;
  };
  float* catbuf  = (float*)alloc((size_t)N * 576 * 4);  // [x1|x2|x3|feats]
  float* h0      = (float*)alloc((size_t)N * 134 * 4);
  float* Abuf    = (float*)alloc((size_t)N * 256 * 4);
  float* Pbbuf   = (float*)alloc((size_t)N * 256 * 4);
  float* sqbuf   = (float*)alloc((size_t)N * 4);
  int*   idxbuf  = (int*)  alloc((size_t)N * KNN * 4);
  float* partial = (float*)alloc((size_t)NBATCH * (PPB / 16) * 1024 * 4);
  float* g       = (float*)alloc((size_t)NBATCH * 1024 * 4);
  float* ga      = (float*)alloc((size_t)NBATCH * 512 * 4);
  float* gb      = (float*)alloc((size_t)NBATCH * 256 * 4);
  (void)ws_size;

  dim3 blk16(16, 16);

  // 1. feats = features @ Wf.T + bf  -> catbuf[:,448:576]
  gemm_kernel<<<dim3(128 / 16, N / 16), blk16, 0, stream>>>(
      features, 1344, Wf, 1344, bf, catbuf + 448, 576, N, 1344, 128);

  // 2. h0 = [pos | x | feats]
  h0_kernel<<<N, 192, 0, stream>>>(pos, xin, catbuf, h0);

  // ---- EdgeConv layers ----
  struct Layer {
    const float* Xin; int ldx; int D;
    const float* W; int ldw;
    const float* bias; int M;
    float* Yout;
  };
  Layer layers[3] = {
      {h0,           134, 134, W1, 268, b1,  64, catbuf + 0},
      {catbuf + 0,   576,  64, W2, 128, b2, 128, catbuf + 64},
      {catbuf + 64,  576, 128, W3, 256, b3, 256, catbuf + 192},
  };

  for (int l = 0; l < 3; ++l) {
    Layer& L = layers[l];
    sq_kernel<<<N, 64, 0, stream>>>(L.Xin, L.ldx, L.D, sqbuf);
    knn_kernel<<<N, 256, 0, stream>>>(L.Xin, L.ldx, L.D, sqbuf, idxbuf);
    // A = X @ Wa.T ; Pb = X @ Wb.T
    gemm_kernel<<<dim3(L.M / 16, N / 16), blk16, 0, stream>>>(
        L.Xin, L.ldx, L.W, L.ldw, (const float*)nullptr, Abuf, L.M, N, L.D, L.M);
    gemm_kernel<<<dim3(L.M / 16, N / 16), blk16, 0, stream>>>(
        L.Xin, L.ldx, L.W + L.D, L.ldw, (const float*)nullptr, Pbbuf, L.M, N, L.D, L.M);
    edge_out_kernel<<<N, 256, 0, stream>>>(
        Abuf, Pbbuf, L.M, L.bias, idxbuf, L.Yout, 576);
  }

  // ---- fc1 + max over points ----
  fc1max_kernel<<<dim3(1024 / 16, PPB / 16, NBATCH), blk16, 0, stream>>>(
      catbuf, 576, Wfc1, 576, bfc1, partial, 576, 1024);
  gmax_kernel<<<dim3(1024 / 256, NBATCH), 256, 0, stream>>>(partial, g);

  // ---- head MLP ----
  mlp_kernel<<<dim3(2, NBATCH), 256, 0, stream>>>(g,  Wfa, bfa, ga, 1024, 512, 1);
  mlp_kernel<<<dim3(1, NBATCH), 256, 0, stream>>>(ga, Wfb, bfb, gb, 512, 256, 1);
  final_kernel<<<NBATCH, 64, 0, stream>>>(gb, Wfc, bfc, out);
}

// Round 2
// 3014.728 us; speedup vs baseline: 2.9854x; 2.9854x over previous
//
#include <hip/hip_runtime.h>
#include <math.h>

#define PPB 2048
#define NBATCH 8
#define KNN 20

// ---------------------------------------------------------------------------
// Register-tiled fp32 GEMM: Y[i][m] = sum_k X[i*ldx+k]*W[m*ldw+k] (+bias[m])
// Block tile 128(i) x BN(m), thread tile 8 x TN, K-tile 8, 256 threads.
// Requires: grid covers exactly N/128 x M/BN.  D arbitrary (zero-padded).
// ---------------------------------------------------------------------------
template <int BN, int TN>
__global__ __launch_bounds__(256) void gemm_kernel(
    const float* __restrict__ X, int ldx,
    const float* __restrict__ W, int ldw,
    const float* __restrict__ bias,
    float* __restrict__ Y, int ldy, int D) {
  __shared__ float Xs[8][132];
  __shared__ float Ws[8][BN + 4];
  int t = threadIdx.x;
  int tx = t & 15, ty = t >> 4;
  int i0 = blockIdx.y * 128, m0 = blockIdx.x * BN;
  float acc[8][TN];
#pragma unroll
  for (int r = 0; r < 8; ++r)
#pragma unroll
    for (int n = 0; n < TN; ++n) acc[r][n] = 0.f;

  for (int k0 = 0; k0 < D; k0 += 8) {
#pragma unroll
    for (int p = 0; p < 4; ++p) {
      int e = t + p * 256, r = e >> 3, c = e & 7, k = k0 + c;
      Xs[c][r] = (k < D) ? X[(size_t)(i0 + r) * ldx + k] : 0.f;
    }
#pragma unroll
    for (int p = 0; p < BN * 8 / 256; ++p) {
      int e = t + p * 256, r = e >> 3, c = e & 7, k = k0 + c;
      Ws[c][r] = (k < D) ? W[(size_t)(m0 + r) * ldw + k] : 0.f;
    }
    __syncthreads();
#pragma unroll
    for (int k = 0; k < 8; ++k) {
      float4 a0 = *(const float4*)&Xs[k][ty * 8];
      float4 a1 = *(const float4*)&Xs[k][ty * 8 + 4];
      float a[8] = {a0.x, a0.y, a0.z, a0.w, a1.x, a1.y, a1.z, a1.w};
      float b[TN];
#pragma unroll
      for (int n4 = 0; n4 < TN / 4; ++n4) {
        float4 bb = *(const float4*)&Ws[k][tx * TN + n4 * 4];
        b[n4 * 4 + 0] = bb.x; b[n4 * 4 + 1] = bb.y;
        b[n4 * 4 + 2] = bb.z; b[n4 * 4 + 3] = bb.w;
      }
#pragma unroll
      for (int r = 0; r < 8; ++r)
#pragma unroll
        for (int n = 0; n < TN; ++n) acc[r][n] += a[r] * b[n];
    }
    __syncthreads();
  }
#pragma unroll
  for (int r = 0; r < 8; ++r) {
    size_t row = (size_t)(i0 + ty * 8 + r) * ldy + m0 + tx * TN;
#pragma unroll
    for (int n4 = 0; n4 < TN / 4; ++n4) {
      float4 o;
      o.x = acc[r][n4 * 4 + 0]; o.y = acc[r][n4 * 4 + 1];
      o.z = acc[r][n4 * 4 + 2]; o.w = acc[r][n4 * 4 + 3];
      if (bias) {
        const float* bp = bias + m0 + tx * TN + n4 * 4;
        o.x += bp[0]; o.y += bp[1]; o.z += bp[2]; o.w += bp[3];
      }
      *(float4*)&Y[row + n4 * 4] = o;
    }
  }
}

// ---------------------------------------------------------------------------
// fc1 GEMM (576 -> 1024) fused with max over the 128-point block tile.
// grid: (1024/128, 2048/128, NBATCH)
// ---------------------------------------------------------------------------
__global__ __launch_bounds__(256) void fc1max_kernel(
    const float* __restrict__ X, int ldx,
    const float* __restrict__ W, int ldw,
    const float* __restrict__ bias,
    float* __restrict__ partial, int D) {
  __shared__ float Xs[8][132];
  __shared__ float Ws[8][132];
  __shared__ float red[16][128];
  int t = threadIdx.x;
  int tx = t & 15, ty = t >> 4;
  int b = blockIdx.z, pt = blockIdx.y;
  int i0 = b * PPB + pt * 128;
  int m0 = blockIdx.x * 128;
  float acc[8][8];
#pragma unroll
  for (int r = 0; r < 8; ++r)
#pragma unroll
    for (int n = 0; n < 8; ++n) acc[r][n] = 0.f;

  for (int k0 = 0; k0 < D; k0 += 8) {
#pragma unroll
    for (int p = 0; p < 4; ++p) {
      int e = t + p * 256, r = e >> 3, c = e & 7, k = k0 + c;
      Xs[c][r] = (k < D) ? X[(size_t)(i0 + r) * ldx + k] : 0.f;
      Ws[c][r] = (k < D) ? W[(size_t)(m0 + r) * ldw + k] : 0.f;
    }
    __syncthreads();
#pragma unroll
    for (int k = 0; k < 8; ++k) {
      float4 a0 = *(const float4*)&Xs[k][ty * 8];
      float4 a1 = *(const float4*)&Xs[k][ty * 8 + 4];
      float a[8] = {a0.x, a0.y, a0.z, a0.w, a1.x, a1.y, a1.z, a1.w};
      float4 b0 = *(const float4*)&Ws[k][tx * 8];
      float4 b1 = *(const float4*)&Ws[k][tx * 8 + 4];
      float bb[8] = {b0.x, b0.y, b0.z, b0.w, b1.x, b1.y, b1.z, b1.w};
#pragma unroll
      for (int r = 0; r < 8; ++r)
#pragma unroll
        for (int n = 0; n < 8; ++n) acc[r][n] += a[r] * bb[n];
    }
    __syncthreads();
  }
  // per-thread max over its 8 rows, +bias
  float tmax[8];
#pragma unroll
  for (int n = 0; n < 8; ++n) {
    float m = acc[0][n];
#pragma unroll
    for (int r = 1; r < 8; ++r) m = fmaxf(m, acc[r][n]);
    tmax[n] = m + bias[m0 + tx * 8 + n];
  }
#pragma unroll
  for (int n = 0; n < 8; ++n) red[ty][tx * 8 + n] = tmax[n];
  __syncthreads();
  for (int off = 8; off > 0; off >>= 1) {
    if (ty < off) {
#pragma unroll
      for (int n = 0; n < 8; ++n)
        red[ty][tx * 8 + n] = fmaxf(red[ty][tx * 8 + n], red[ty + off][tx * 8 + n]);
    }
    __syncthreads();
  }
  if (ty == 0) {
#pragma unroll
    for (int n = 0; n < 8; ++n)
      partial[((size_t)b * 16 + pt) * 1024 + m0 + tx * 8 + n] = red[0][tx * 8 + n];
  }
}

__global__ __launch_bounds__(256) void gmax_kernel(
    const float* __restrict__ partial, float* __restrict__ g) {
  int b = blockIdx.y;
  int m = blockIdx.x * 256 + threadIdx.x;
  float mx = -INFINITY;
  for (int pt = 0; pt < 16; ++pt)
    mx = fmaxf(mx, partial[((size_t)b * 16 + pt) * 1024 + m]);
  g[b * 1024 + m] = mx;
}

// ---------------------------------------------------------------------------
// h0 = [pos | x | feats]
// ---------------------------------------------------------------------------
__global__ __launch_bounds__(192) void h0_kernel(
    const float* __restrict__ pos, const float* __restrict__ xin,
    const float* __restrict__ catbuf, float* __restrict__ h0) {
  int i = blockIdx.x;
  int d = threadIdx.x;
  if (d < 3)        h0[(size_t)i * 134 + d] = pos[i * 3 + d];
  else if (d < 6)   h0[(size_t)i * 134 + d] = xin[i * 3 + d - 3];
  else if (d < 134) h0[(size_t)i * 134 + d] = catbuf[(size_t)i * 576 + 448 + (d - 6)];
}

// ---------------------------------------------------------------------------
// sq[i] = sum_k X[i][k]^2
// ---------------------------------------------------------------------------
__global__ __launch_bounds__(64) void sq_kernel(
    const float* __restrict__ X, int ldx, int D, float* __restrict__ sq) {
  int i = blockIdx.x;
  int t = threadIdx.x;
  float s = 0.f;
  for (int k = t; k < D; k += 64) {
    float v = X[(size_t)i * ldx + k];
    s += v * v;
  }
  for (int off = 32; off > 0; off >>= 1) s += __shfl_down(s, off);
  if (t == 0) sq[i] = s;
}

// ---------------------------------------------------------------------------
// Transpose per batch: XT[b][k][j] = X[b*PPB+j][k]
// grid: (PPB/64, ceil(D/64), NBATCH), block 256
// ---------------------------------------------------------------------------
__global__ __launch_bounds__(256) void transpose_kernel(
    const float* __restrict__ X, int ldx, int D, float* __restrict__ XT) {
  __shared__ float Ts[64][65];
  int b = blockIdx.z;
  int j0 = blockIdx.x * 64;
  int k0 = blockIdx.y * 64;
  int t = threadIdx.x;
#pragma unroll
  for (int p = 0; p < 16; ++p) {
    int e = t + p * 256, r = e >> 6, c = e & 63;
    Ts[r][c] = (k0 + c < D) ? X[(size_t)(b * PPB + j0 + r) * ldx + k0 + c] : 0.f;
  }
  __syncthreads();
#pragma unroll
  for (int p = 0; p < 16; ++p) {
    int e = t + p * 256, r = e >> 6, c = e & 63;
    if (k0 + r < D)
      XT[((size_t)b * D + k0 + r) * PPB + j0 + c] = Ts[c][r];
  }
}

// ---------------------------------------------------------------------------
// Fused dist + top-K.  16 queries/block, 256 threads (4 waves).
// Thread t owns candidates j = t + 256*s, s=0..7.  Rank on sq[j]-2*dot
// (row-constant sq[i] dropped; ranking identical).
// grid: (PPB/16, NBATCH)
// ---------------------------------------------------------------------------
__global__ __launch_bounds__(256) void knn2_kernel(
    const float* __restrict__ X, int ldx,
    const float* __restrict__ XT,
    const float* __restrict__ sq, int D,
    int* __restrict__ idx) {
  __shared__ float Qs[134][16];
  __shared__ float dist4[4][PPB];
  int b = blockIdx.y;
  int q0 = blockIdx.x * 16;
  int t = threadIdx.x;
  int lane = t & 63, w = t >> 6;

  for (int e = t; e < 16 * D; e += 256) {
    int q = e / D, k = e - q * D;
    Qs[k][q] = X[(size_t)(b * PPB + q0 + q) * ldx + k];
  }
  __syncthreads();

  const float* XTb = XT + (size_t)b * D * PPB;
  float acc[16][8];
#pragma unroll
  for (int q = 0; q < 16; ++q)
#pragma unroll
    for (int s = 0; s < 8; ++s) acc[q][s] = 0.f;

  for (int k = 0; k < D; ++k) {
    float cv[8];
    const float* cp = XTb + (size_t)k * PPB + t;
#pragma unroll
    for (int s = 0; s < 8; ++s) cv[s] = cp[256 * s];
    float4 q0v = *(const float4*)&Qs[k][0];
    float4 q1v = *(const float4*)&Qs[k][4];
    float4 q2v = *(const float4*)&Qs[k][8];
    float4 q3v = *(const float4*)&Qs[k][12];
    float qv[16] = {q0v.x, q0v.y, q0v.z, q0v.w, q1v.x, q1v.y, q1v.z, q1v.w,
                    q2v.x, q2v.y, q2v.z, q2v.w, q3v.x, q3v.y, q3v.z, q3v.w};
#pragma unroll
    for (int q = 0; q < 16; ++q)
#pragma unroll
      for (int s = 0; s < 8; ++s) acc[q][s] += qv[q] * cv[s];
  }

  float sqj[8];
#pragma unroll
  for (int s = 0; s < 8; ++s) sqj[s] = sq[b * PPB + t + 256 * s];

#pragma unroll
  for (int r = 0; r < 4; ++r) {
#pragma unroll
    for (int qq = 0; qq < 4; ++qq)
#pragma unroll
      for (int s = 0; s < 8; ++s)
        dist4[qq][t + 256 * s] = sqj[s] - 2.f * acc[r * 4 + qq][s];
    __syncthreads();
    {
      // wave w selects top-K for query r*4+w
      float v[32];
#pragma unroll
      for (int m = 0; m < 32; ++m) v[m] = dist4[w][lane + 64 * m];
#pragma unroll
      for (int s = 0; s < KNN; ++s) {
        float bv = 1e38f;
        int bm = 0;
#pragma unroll
        for (int m = 0; m < 32; ++m)
          if (v[m] < bv) { bv = v[m]; bm = m; }
        int bj = lane + 64 * bm;
#pragma unroll
        for (int o = 1; o < 64; o <<= 1) {
          float ov = __shfl_xor(bv, o);
          int oj = __shfl_xor(bj, o);
          if (ov < bv || (ov == bv && oj < bj)) { bv = ov; bj = oj; }
        }
        if (lane == 0)
          idx[(size_t)(b * PPB + q0 + r * 4 + w) * KNN + s] = b * PPB + bj;
        bool mine = (lane == (bj & 63));
        int wm = bj >> 6;
#pragma unroll
        for (int m = 0; m < 32; ++m)
          if (mine && m == wm) v[m] = 1e38f;
      }
    }
    __syncthreads();
  }
}

// ---------------------------------------------------------------------------
// EdgeConv epilogue: Y[i][m] = A[i][m] + b[m] - Pb[i][m] + max_kk Pb[nb][m]
// ---------------------------------------------------------------------------
__global__ __launch_bounds__(256) void edge_out_kernel(
    const float* __restrict__ A, const float* __restrict__ Pb, int M,
    const float* __restrict__ bias, const int* __restrict__ idx,
    float* __restrict__ Y, int ldy) {
  int i = blockIdx.x;
  int t = threadIdx.x;
  __shared__ int nbs[KNN];
  if (t < KNN) nbs[t] = idx[(size_t)i * KNN + t];
  __syncthreads();
  for (int m = t; m < M; m += 256) {
    float mx = -INFINITY;
#pragma unroll
    for (int kk = 0; kk < KNN; ++kk)
      mx = fmaxf(mx, Pb[(size_t)nbs[kk] * M + m]);
    Y[(size_t)i * ldy + m] = A[(size_t)i * M + m] + bias[m] - Pb[(size_t)i * M + m] + mx;
  }
}

// ---------------------------------------------------------------------------
// Tiny per-batch MLP layer
// ---------------------------------------------------------------------------
__global__ __launch_bounds__(256) void mlp_kernel(
    const float* __restrict__ X, const float* __restrict__ W,
    const float* __restrict__ bias, float* __restrict__ Y,
    int D, int M, int do_relu) {
  int b = blockIdx.y;
  int m = blockIdx.x * 256 + threadIdx.x;
  if (m >= M) return;
  const float* xr = X + (size_t)b * D;
  const float* wr = W + (size_t)m * D;
  float acc = 0.f;
  for (int k = 0; k < D; ++k) acc += xr[k] * wr[k];
  acc += bias[m];
  if (do_relu) acc = fmaxf(acc, 0.f);
  Y[(size_t)b * M + m] = acc;
}

__global__ __launch_bounds__(64) void final_kernel(
    const float* __restrict__ X, const float* __restrict__ W,
    const float* __restrict__ bias, float* __restrict__ out) {
  int b = blockIdx.x;
  int t = threadIdx.x;
  __shared__ float lg[23];
  if (t < 23) {
    const float* xr = X + (size_t)b * 256;
    const float* wr = W + (size_t)t * 256;
    float acc = bias[t];
    for (int k = 0; k < 256; ++k) acc += xr[k] * wr[k];
    lg[t] = acc;
  }
  __syncthreads();
  if (t == 0) {
    float mx = lg[0];
    for (int c = 1; c < 23; ++c) mx = fmaxf(mx, lg[c]);
    float s = 0.f;
    for (int c = 0; c < 23; ++c) s += expf(lg[c] - mx);
    float lse = mx + logf(s);
    for (int c = 0; c < 23; ++c) out[b * 23 + c] = lg[c] - lse;
  }
}

// ---------------------------------------------------------------------------

extern "C" void kernel_launch(void* const* d_in, const int* in_sizes, int n_in,
                              void* d_out, int out_size, void* d_ws, size_t ws_size,
                              hipStream_t stream) {
  const float* pos      = (const float*)d_in[0];
  const float* xin      = (const float*)d_in[1];
  const float* features = (const float*)d_in[2];
  const float* Wf   = (const float*)d_in[4];
  const float* bf   = (const float*)d_in[5];
  const float* W1   = (const float*)d_in[6];
  const float* b1   = (const float*)d_in[7];
  const float* W2   = (const float*)d_in[8];
  const float* b2   = (const float*)d_in[9];
  const float* W3   = (const float*)d_in[10];
  const float* b3   = (const float*)d_in[11];
  const float* Wfc1 = (const float*)d_in[12];
  const float* bfc1 = (const float*)d_in[13];
  const float* Wfa  = (const float*)d_in[14];
  const float* bfa  = (const float*)d_in[15];
  const float* Wfb  = (const float*)d_in[16];
  const float* bfb  = (const float*)d_in[17];
  const float* Wfc  = (const float*)d_in[18];
  const float* bfc  = (const float*)d_in[19];
  float* out = (float*)d_out;

  const int N = in_sizes[0] / 3;  // 16384

  char* base = (char*)d_ws;
  size_t off = 0;
  auto alloc = [&](size_t bytes) {
    void* p = base + off;
    off += (bytes + 255) & ~(size_t)255;
    return p;
  };
  float* catbuf  = (float*)alloc((size_t)N * 576 * 4);  // [x1|x2|x3|feats]
  float* h0      = (float*)alloc((size_t)N * 134 * 4);
  float* Abuf    = (float*)alloc((size_t)N * 256 * 4);
  float* Pbbuf   = (float*)alloc((size_t)N * 256 * 4);
  float* XTbuf   = (float*)alloc((size_t)N * 134 * 4);
  float* sqbuf   = (float*)alloc((size_t)N * 4);
  int*   idxbuf  = (int*)  alloc((size_t)N * KNN * 4);
  float* partial = (float*)alloc((size_t)NBATCH * 16 * 1024 * 4);
  float* g       = (float*)alloc((size_t)NBATCH * 1024 * 4);
  float* ga      = (float*)alloc((size_t)NBATCH * 512 * 4);
  float* gb      = (float*)alloc((size_t)NBATCH * 256 * 4);
  (void)ws_size;

  // 1. feats = features @ Wf.T + bf  -> catbuf[:,448:576]
  gemm_kernel<128, 8><<<dim3(1, N / 128), 256, 0, stream>>>(
      features, 1344, Wf, 1344, bf, catbuf + 448, 576, 1344);

  // 2. h0 = [pos | x | feats]
  h0_kernel<<<N, 192, 0, stream>>>(pos, xin, catbuf, h0);

  struct Layer {
    const float* Xin; int ldx; int D;
    const float* W; int ldw;
    const float* bias; int M;
    float* Yout;
  };
  Layer L[3] = {
      {h0,          134, 134, W1, 268, b1,  64, catbuf + 0},
      {catbuf + 0,  576,  64, W2, 128, b2, 128, catbuf + 64},
      {catbuf + 64, 576, 128, W3, 256, b3, 256, catbuf + 192},
  };

  for (int l = 0; l < 3; ++l) {
    sq_kernel<<<N, 64, 0, stream>>>(L[l].Xin, L[l].ldx, L[l].D, sqbuf);
    transpose_kernel<<<dim3(PPB / 64, (L[l].D + 63) / 64, NBATCH), 256, 0, stream>>>(
        L[l].Xin, L[l].ldx, L[l].D, XTbuf);
    knn2_kernel<<<dim3(PPB / 16, NBATCH), 256, 0, stream>>>(
        L[l].Xin, L[l].ldx, XTbuf, sqbuf, L[l].D, idxbuf);
    // A = X @ Wa.T ; Pb = X @ Wb.T
    if (L[l].M == 64) {
      gemm_kernel<64, 4><<<dim3(1, N / 128), 256, 0, stream>>>(
          L[l].Xin, L[l].ldx, L[l].W, L[l].ldw, nullptr, Abuf, 64, L[l].D);
      gemm_kernel<64, 4><<<dim3(1, N / 128), 256, 0, stream>>>(
          L[l].Xin, L[l].ldx, L[l].W + L[l].D, L[l].ldw, nullptr, Pbbuf, 64, L[l].D);
    } else {
      gemm_kernel<128, 8><<<dim3(L[l].M / 128, N / 128), 256, 0, stream>>>(
          L[l].Xin, L[l].ldx, L[l].W, L[l].ldw, nullptr, Abuf, L[l].M, L[l].D);
      gemm_kernel<128, 8><<<dim3(L[l].M / 128, N / 128), 256, 0, stream>>>(
          L[l].Xin, L[l].ldx, L[l].W + L[l].D, L[l].ldw, nullptr, Pbbuf, L[l].M, L[l].D);
    }
    edge_out_kernel<<<N, 256, 0, stream>>>(
        Abuf, Pbbuf, L[l].M, L[l].bias, idxbuf, L[l].Yout, 576);
  }

  // fc1 + max over points
  fc1max_kernel<<<dim3(1024 / 128, PPB / 128, NBATCH), 256, 0, stream>>>(
      catbuf, 576, Wfc1, 576, bfc1, partial, 576);
  gmax_kernel<<<dim3(1024 / 256, NBATCH), 256, 0, stream>>>(partial, g);

  // head MLP
  mlp_kernel<<<dim3(2, NBATCH), 256, 0, stream>>>(g,  Wfa, bfa, ga, 1024, 512, 1);
  mlp_kernel<<<dim3(1, NBATCH), 256, 0, stream>>>(ga, Wfb, bfb, gb, 512, 256, 1);
  final_kernel<<<NBATCH, 64, 0, stream>>>(gb, Wfc, bfc, out);
}

// Round 3
// 2114.177 us; speedup vs baseline: 4.2570x; 1.4260x over previous
//
#include <hip/hip_runtime.h>
#include <math.h>

#define PPB 2048
#define NBATCH 8
#define KNN 20

// ---------------------------------------------------------------------------
// Register-tiled fp32 GEMM: Y[i][m] = sum_k X[i*ldx+k]*W[m*ldw+k] (+bias[m])
// Block tile 128(i) x BN(m), thread tile 8 x TN, K-tile 8, 256 threads.
// ---------------------------------------------------------------------------
template <int BN, int TN>
__global__ __launch_bounds__(256) void gemm_kernel(
    const float* __restrict__ X, int ldx,
    const float* __restrict__ W, int ldw,
    const float* __restrict__ bias,
    float* __restrict__ Y, int ldy, int D) {
  __shared__ float Xs[8][132];
  __shared__ float Ws[8][BN + 4];
  int t = threadIdx.x;
  int tx = t & 15, ty = t >> 4;
  int i0 = blockIdx.y * 128, m0 = blockIdx.x * BN;
  float acc[8][TN];
#pragma unroll
  for (int r = 0; r < 8; ++r)
#pragma unroll
    for (int n = 0; n < TN; ++n) acc[r][n] = 0.f;

  for (int k0 = 0; k0 < D; k0 += 8) {
#pragma unroll
    for (int p = 0; p < 4; ++p) {
      int e = t + p * 256, r = e >> 3, c = e & 7, k = k0 + c;
      Xs[c][r] = (k < D) ? X[(size_t)(i0 + r) * ldx + k] : 0.f;
    }
#pragma unroll
    for (int p = 0; p < BN * 8 / 256; ++p) {
      int e = t + p * 256, r = e >> 3, c = e & 7, k = k0 + c;
      Ws[c][r] = (k < D) ? W[(size_t)(m0 + r) * ldw + k] : 0.f;
    }
    __syncthreads();
#pragma unroll
    for (int k = 0; k < 8; ++k) {
      float4 a0 = *(const float4*)&Xs[k][ty * 8];
      float4 a1 = *(const float4*)&Xs[k][ty * 8 + 4];
      float a[8] = {a0.x, a0.y, a0.z, a0.w, a1.x, a1.y, a1.z, a1.w};
      float b[TN];
#pragma unroll
      for (int n4 = 0; n4 < TN / 4; ++n4) {
        float4 bb = *(const float4*)&Ws[k][tx * TN + n4 * 4];
        b[n4 * 4 + 0] = bb.x; b[n4 * 4 + 1] = bb.y;
        b[n4 * 4 + 2] = bb.z; b[n4 * 4 + 3] = bb.w;
      }
#pragma unroll
      for (int r = 0; r < 8; ++r)
#pragma unroll
        for (int n = 0; n < TN; ++n) acc[r][n] += a[r] * b[n];
    }
    __syncthreads();
  }
#pragma unroll
  for (int r = 0; r < 8; ++r) {
    size_t row = (size_t)(i0 + ty * 8 + r) * ldy + m0 + tx * TN;
#pragma unroll
    for (int n4 = 0; n4 < TN / 4; ++n4) {
      float4 o;
      o.x = acc[r][n4 * 4 + 0]; o.y = acc[r][n4 * 4 + 1];
      o.z = acc[r][n4 * 4 + 2]; o.w = acc[r][n4 * 4 + 3];
      if (bias) {
        const float* bp = bias + m0 + tx * TN + n4 * 4;
        o.x += bp[0]; o.y += bp[1]; o.z += bp[2]; o.w += bp[3];
      }
      *(float4*)&Y[row + n4 * 4] = o;
    }
  }
}

// ---------------------------------------------------------------------------
// fc1 GEMM (576 -> 1024) fused with max over the 128-point block tile.
// ---------------------------------------------------------------------------
__global__ __launch_bounds__(256) void fc1max_kernel(
    const float* __restrict__ X, int ldx,
    const float* __restrict__ W, int ldw,
    const float* __restrict__ bias,
    float* __restrict__ partial, int D) {
  __shared__ float Xs[8][132];
  __shared__ float Ws[8][132];
  __shared__ float red[16][128];
  int t = threadIdx.x;
  int tx = t & 15, ty = t >> 4;
  int b = blockIdx.z, pt = blockIdx.y;
  int i0 = b * PPB + pt * 128;
  int m0 = blockIdx.x * 128;
  float acc[8][8];
#pragma unroll
  for (int r = 0; r < 8; ++r)
#pragma unroll
    for (int n = 0; n < 8; ++n) acc[r][n] = 0.f;

  for (int k0 = 0; k0 < D; k0 += 8) {
#pragma unroll
    for (int p = 0; p < 4; ++p) {
      int e = t + p * 256, r = e >> 3, c = e & 7, k = k0 + c;
      Xs[c][r] = (k < D) ? X[(size_t)(i0 + r) * ldx + k] : 0.f;
      Ws[c][r] = (k < D) ? W[(size_t)(m0 + r) * ldw + k] : 0.f;
    }
    __syncthreads();
#pragma unroll
    for (int k = 0; k < 8; ++k) {
      float4 a0 = *(const float4*)&Xs[k][ty * 8];
      float4 a1 = *(const float4*)&Xs[k][ty * 8 + 4];
      float a[8] = {a0.x, a0.y, a0.z, a0.w, a1.x, a1.y, a1.z, a1.w};
      float4 b0 = *(const float4*)&Ws[k][tx * 8];
      float4 b1 = *(const float4*)&Ws[k][tx * 8 + 4];
      float bb[8] = {b0.x, b0.y, b0.z, b0.w, b1.x, b1.y, b1.z, b1.w};
#pragma unroll
      for (int r = 0; r < 8; ++r)
#pragma unroll
        for (int n = 0; n < 8; ++n) acc[r][n] += a[r] * bb[n];
    }
    __syncthreads();
  }
  float tmax[8];
#pragma unroll
  for (int n = 0; n < 8; ++n) {
    float m = acc[0][n];
#pragma unroll
    for (int r = 1; r < 8; ++r) m = fmaxf(m, acc[r][n]);
    tmax[n] = m + bias[m0 + tx * 8 + n];
  }
#pragma unroll
  for (int n = 0; n < 8; ++n) red[ty][tx * 8 + n] = tmax[n];
  __syncthreads();
  for (int off = 8; off > 0; off >>= 1) {
    if (ty < off) {
#pragma unroll
      for (int n = 0; n < 8; ++n)
        red[ty][tx * 8 + n] = fmaxf(red[ty][tx * 8 + n], red[ty + off][tx * 8 + n]);
    }
    __syncthreads();
  }
  if (ty == 0) {
#pragma unroll
    for (int n = 0; n < 8; ++n)
      partial[((size_t)b * 16 + pt) * 1024 + m0 + tx * 8 + n] = red[0][tx * 8 + n];
  }
}

__global__ __launch_bounds__(256) void gmax_kernel(
    const float* __restrict__ partial, float* __restrict__ g) {
  int b = blockIdx.y;
  int m = blockIdx.x * 256 + threadIdx.x;
  float mx = -INFINITY;
  for (int pt = 0; pt < 16; ++pt)
    mx = fmaxf(mx, partial[((size_t)b * 16 + pt) * 1024 + m]);
  g[b * 1024 + m] = mx;
}

// ---------------------------------------------------------------------------
__global__ __launch_bounds__(192) void h0_kernel(
    const float* __restrict__ pos, const float* __restrict__ xin,
    const float* __restrict__ catbuf, float* __restrict__ h0) {
  int i = blockIdx.x;
  int d = threadIdx.x;
  if (d < 3)        h0[(size_t)i * 134 + d] = pos[i * 3 + d];
  else if (d < 6)   h0[(size_t)i * 134 + d] = xin[i * 3 + d - 3];
  else if (d < 134) h0[(size_t)i * 134 + d] = catbuf[(size_t)i * 576 + 448 + (d - 6)];
}

__global__ __launch_bounds__(64) void sq_kernel(
    const float* __restrict__ X, int ldx, int D, float* __restrict__ sq) {
  int i = blockIdx.x;
  int t = threadIdx.x;
  float s = 0.f;
  for (int k = t; k < D; k += 64) {
    float v = X[(size_t)i * ldx + k];
    s += v * v;
  }
  for (int off = 32; off > 0; off >>= 1) s += __shfl_down(s, off);
  if (t == 0) sq[i] = s;
}

// ---------------------------------------------------------------------------
// Transpose per batch: XT[b][k][j] = X[b*PPB+j][k]
// ---------------------------------------------------------------------------
__global__ __launch_bounds__(256) void transpose_kernel(
    const float* __restrict__ X, int ldx, int D, float* __restrict__ XT) {
  __shared__ float Ts[64][65];
  int b = blockIdx.z;
  int j0 = blockIdx.x * 64;
  int k0 = blockIdx.y * 64;
  int t = threadIdx.x;
#pragma unroll
  for (int p = 0; p < 16; ++p) {
    int e = t + p * 256, r = e >> 6, c = e & 63;
    Ts[r][c] = (k0 + c < D) ? X[(size_t)(b * PPB + j0 + r) * ldx + k0 + c] : 0.f;
  }
  __syncthreads();
#pragma unroll
  for (int p = 0; p < 16; ++p) {
    int e = t + p * 256, r = e >> 6, c = e & 63;
    if (k0 + r < D)
      XT[((size_t)b * D + k0 + r) * PPB + j0 + c] = Ts[c][r];
  }
}

// ---------------------------------------------------------------------------
// Fused dist + top-K, spill-free.  8 queries/block, 256 threads (4 waves).
// Thread t owns candidates j = t + 256*s, s=0..7.  acc[8][8] = 64 VGPRs.
// After MAC loop all 8 dist rows go to LDS; acc dead during selection.
// Rank on sq[j]-2*dot (row-constant sq[i] dropped; ranking identical).
// grid: (PPB/8, NBATCH)
// ---------------------------------------------------------------------------
template <int D>
__global__ __launch_bounds__(256) void knn3_kernel(
    const float* __restrict__ X, int ldx,
    const float* __restrict__ XT,
    const float* __restrict__ sq,
    int* __restrict__ idx) {
  __shared__ float Qs[D][8];
  __shared__ float dist[8][PPB];
  int b = blockIdx.y;
  int q0 = blockIdx.x * 8;
  int t = threadIdx.x;
  int lane = t & 63, w = t >> 6;

  for (int e = t; e < 8 * D; e += 256) {
    int q = e / D, k = e - q * D;
    Qs[k][q] = X[(size_t)(b * PPB + q0 + q) * ldx + k];
  }
  __syncthreads();

  const float* XTb = XT + (size_t)b * D * PPB;
  float acc[8][8];
#pragma unroll
  for (int q = 0; q < 8; ++q)
#pragma unroll
    for (int s = 0; s < 8; ++s) acc[q][s] = 0.f;

#pragma unroll 2
  for (int k = 0; k < D; ++k) {
    float cv[8];
    const float* cp = XTb + (size_t)k * PPB + t;
#pragma unroll
    for (int s = 0; s < 8; ++s) cv[s] = cp[256 * s];
    float4 q0v = *(const float4*)&Qs[k][0];
    float4 q1v = *(const float4*)&Qs[k][4];
    float qv[8] = {q0v.x, q0v.y, q0v.z, q0v.w, q1v.x, q1v.y, q1v.z, q1v.w};
#pragma unroll
    for (int q = 0; q < 8; ++q)
#pragma unroll
      for (int s = 0; s < 8; ++s) acc[q][s] += qv[q] * cv[s];
  }

  float sqj[8];
#pragma unroll
  for (int s = 0; s < 8; ++s) sqj[s] = sq[b * PPB + t + 256 * s];

#pragma unroll
  for (int q = 0; q < 8; ++q)
#pragma unroll
    for (int s = 0; s < 8; ++s)
      dist[q][t + 256 * s] = sqj[s] - 2.f * acc[q][s];
  __syncthreads();

  // wave w selects top-K for rows q = 2*w and 2*w+1
#pragma unroll
  for (int rr = 0; rr < 2; ++rr) {
    int q = w * 2 + rr;
    float v[32];
#pragma unroll
    for (int m = 0; m < 32; ++m) v[m] = dist[q][lane + 64 * m];
#pragma unroll
    for (int s = 0; s < KNN; ++s) {
      float bv = 1e38f;
      int bm = 0;
#pragma unroll
      for (int m = 0; m < 32; ++m)
        if (v[m] < bv) { bv = v[m]; bm = m; }
      int bj = lane + 64 * bm;
#pragma unroll
      for (int o = 1; o < 64; o <<= 1) {
        float ov = __shfl_xor(bv, o);
        int oj = __shfl_xor(bj, o);
        if (ov < bv || (ov == bv && oj < bj)) { bv = ov; bj = oj; }
      }
      if (lane == 0)
        idx[(size_t)(b * PPB + q0 + q) * KNN + s] = b * PPB + bj;
      bool mine = (lane == (bj & 63));
      int wm = bj >> 6;
#pragma unroll
      for (int m = 0; m < 32; ++m)
        if (mine && m == wm) v[m] = 1e38f;
    }
  }
}

// ---------------------------------------------------------------------------
// EdgeConv epilogue: Y[i][m] = A[i][m] + b[m] - Pb[i][m] + max_kk Pb[nb][m]
// ---------------------------------------------------------------------------
__global__ __launch_bounds__(256) void edge_out_kernel(
    const float* __restrict__ A, const float* __restrict__ Pb, int M,
    const float* __restrict__ bias, const int* __restrict__ idx,
    float* __restrict__ Y, int ldy) {
  int i = blockIdx.x;
  int t = threadIdx.x;
  __shared__ int nbs[KNN];
  if (t < KNN) nbs[t] = idx[(size_t)i * KNN + t];
  __syncthreads();
  for (int m = t; m < M; m += 256) {
    float mx = -INFINITY;
#pragma unroll
    for (int kk = 0; kk < KNN; ++kk)
      mx = fmaxf(mx, Pb[(size_t)nbs[kk] * M + m]);
    Y[(size_t)i * ldy + m] = A[(size_t)i * M + m] + bias[m] - Pb[(size_t)i * M + m] + mx;
  }
}

// ---------------------------------------------------------------------------
__global__ __launch_bounds__(256) void mlp_kernel(
    const float* __restrict__ X, const float* __restrict__ W,
    const float* __restrict__ bias, float* __restrict__ Y,
    int D, int M, int do_relu) {
  int b = blockIdx.y;
  int m = blockIdx.x * 256 + threadIdx.x;
  if (m >= M) return;
  const float* xr = X + (size_t)b * D;
  const float* wr = W + (size_t)m * D;
  float acc = 0.f;
  for (int k = 0; k < D; ++k) acc += xr[k] * wr[k];
  acc += bias[m];
  if (do_relu) acc = fmaxf(acc, 0.f);
  Y[(size_t)b * M + m] = acc;
}

__global__ __launch_bounds__(64) void final_kernel(
    const float* __restrict__ X, const float* __restrict__ W,
    const float* __restrict__ bias, float* __restrict__ out) {
  int b = blockIdx.x;
  int t = threadIdx.x;
  __shared__ float lg[23];
  if (t < 23) {
    const float* xr = X + (size_t)b * 256;
    const float* wr = W + (size_t)t * 256;
    float acc = bias[t];
    for (int k = 0; k < 256; ++k) acc += xr[k] * wr[k];
    lg[t] = acc;
  }
  __syncthreads();
  if (t == 0) {
    float mx = lg[0];
    for (int c = 1; c < 23; ++c) mx = fmaxf(mx, lg[c]);
    float s = 0.f;
    for (int c = 0; c < 23; ++c) s += expf(lg[c] - mx);
    float lse = mx + logf(s);
    for (int c = 0; c < 23; ++c) out[b * 23 + c] = lg[c] - lse;
  }
}

// ---------------------------------------------------------------------------

extern "C" void kernel_launch(void* const* d_in, const int* in_sizes, int n_in,
                              void* d_out, int out_size, void* d_ws, size_t ws_size,
                              hipStream_t stream) {
  const float* pos      = (const float*)d_in[0];
  const float* xin      = (const float*)d_in[1];
  const float* features = (const float*)d_in[2];
  const float* Wf   = (const float*)d_in[4];
  const float* bf   = (const float*)d_in[5];
  const float* W1   = (const float*)d_in[6];
  const float* b1   = (const float*)d_in[7];
  const float* W2   = (const float*)d_in[8];
  const float* b2   = (const float*)d_in[9];
  const float* W3   = (const float*)d_in[10];
  const float* b3   = (const float*)d_in[11];
  const float* Wfc1 = (const float*)d_in[12];
  const float* bfc1 = (const float*)d_in[13];
  const float* Wfa  = (const float*)d_in[14];
  const float* bfa  = (const float*)d_in[15];
  const float* Wfb  = (const float*)d_in[16];
  const float* bfb  = (const float*)d_in[17];
  const float* Wfc  = (const float*)d_in[18];
  const float* bfc  = (const float*)d_in[19];
  float* out = (float*)d_out;

  const int N = in_sizes[0] / 3;  // 16384

  char* base = (char*)d_ws;
  size_t off = 0;
  auto alloc = [&](size_t bytes) {
    void* p = base + off;
    off += (bytes + 255) & ~(size_t)255;
    return p;
  };
  float* catbuf  = (float*)alloc((size_t)N * 576 * 4);  // [x1|x2|x3|feats]
  float* h0      = (float*)alloc((size_t)N * 134 * 4);
  float* Abuf    = (float*)alloc((size_t)N * 256 * 4);
  float* Pbbuf   = (float*)alloc((size_t)N * 256 * 4);
  float* XTbuf   = (float*)alloc((size_t)N * 134 * 4);
  float* sqbuf   = (float*)alloc((size_t)N * 4);
  int*   idxbuf  = (int*)  alloc((size_t)N * KNN * 4);
  float* partial = (float*)alloc((size_t)NBATCH * 16 * 1024 * 4);
  float* g       = (float*)alloc((size_t)NBATCH * 1024 * 4);
  float* ga      = (float*)alloc((size_t)NBATCH * 512 * 4);
  float* gb      = (float*)alloc((size_t)NBATCH * 256 * 4);
  (void)ws_size;

  // 1. feats = features @ Wf.T + bf  -> catbuf[:,448:576]
  gemm_kernel<128, 8><<<dim3(1, N / 128), 256, 0, stream>>>(
      features, 1344, Wf, 1344, bf, catbuf + 448, 576, 1344);

  // 2. h0 = [pos | x | feats]
  h0_kernel<<<N, 192, 0, stream>>>(pos, xin, catbuf, h0);

  struct Layer {
    const float* Xin; int ldx; int D;
    const float* W; int ldw;
    const float* bias; int M;
    float* Yout;
  };
  Layer L[3] = {
      {h0,          134, 134, W1, 268, b1,  64, catbuf + 0},
      {catbuf + 0,  576,  64, W2, 128, b2, 128, catbuf + 64},
      {catbuf + 64, 576, 128, W3, 256, b3, 256, catbuf + 192},
  };

  for (int l = 0; l < 3; ++l) {
    sq_kernel<<<N, 64, 0, stream>>>(L[l].Xin, L[l].ldx, L[l].D, sqbuf);
    transpose_kernel<<<dim3(PPB / 64, (L[l].D + 63) / 64, NBATCH), 256, 0, stream>>>(
        L[l].Xin, L[l].ldx, L[l].D, XTbuf);
    if (L[l].D == 134)
      knn3_kernel<134><<<dim3(PPB / 8, NBATCH), 256, 0, stream>>>(
          L[l].Xin, L[l].ldx, XTbuf, sqbuf, idxbuf);
    else if (L[l].D == 64)
      knn3_kernel<64><<<dim3(PPB / 8, NBATCH), 256, 0, stream>>>(
          L[l].Xin, L[l].ldx, XTbuf, sqbuf, idxbuf);
    else
      knn3_kernel<128><<<dim3(PPB / 8, NBATCH), 256, 0, stream>>>(
          L[l].Xin, L[l].ldx, XTbuf, sqbuf, idxbuf);
    // A = X @ Wa.T ; Pb = X @ Wb.T
    if (L[l].M == 64) {
      gemm_kernel<64, 4><<<dim3(1, N / 128), 256, 0, stream>>>(
          L[l].Xin, L[l].ldx, L[l].W, L[l].ldw, nullptr, Abuf, 64, L[l].D);
      gemm_kernel<64, 4><<<dim3(1, N / 128), 256, 0, stream>>>(
          L[l].Xin, L[l].ldx, L[l].W + L[l].D, L[l].ldw, nullptr, Pbbuf, 64, L[l].D);
    } else {
      gemm_kernel<128, 8><<<dim3(L[l].M / 128, N / 128), 256, 0, stream>>>(
          L[l].Xin, L[l].ldx, L[l].W, L[l].ldw, nullptr, Abuf, L[l].M, L[l].D);
      gemm_kernel<128, 8><<<dim3(L[l].M / 128, N / 128), 256, 0, stream>>>(
          L[l].Xin, L[l].ldx, L[l].W + L[l].D, L[l].ldw, nullptr, Pbbuf, L[l].M, L[l].D);
    }
    edge_out_kernel<<<N, 256, 0, stream>>>(
        Abuf, Pbbuf, L[l].M, L[l].bias, idxbuf, L[l].Yout, 576);
  }

  // fc1 + max over points
  fc1max_kernel<<<dim3(1024 / 128, PPB / 128, NBATCH), 256, 0, stream>>>(
      catbuf, 576, Wfc1, 576, bfc1, partial, 576);
  gmax_kernel<<<dim3(1024 / 256, NBATCH), 256, 0, stream>>>(partial, g);

  // head MLP
  mlp_kernel<<<dim3(2, NBATCH), 256, 0, stream>>>(g,  Wfa, bfa, ga, 1024, 512, 1);
  mlp_kernel<<<dim3(1, NBATCH), 256, 0, stream>>>(ga, Wfb, bfb, gb, 512, 256, 1);
  final_kernel<<<NBATCH, 64, 0, stream>>>(gb, Wfc, bfc, out);
}